// Round 16
// baseline (789.812 us; speedup 1.0000x reference)
//
#include <hip/hip_runtime.h>
#include <hip/hip_bf16.h>
#include <stdint.h>

// SingleStreamBlock fused pipeline, all-bf16 MFMA datapath.
// GEMMs: 256x256 4-phase/K-tile (R13 schedule, FROZEN). gemm1 fuses gelu;
// gemm2 split-K=8 (768 blocks = 3 exact CU rounds) bf16 partials.
// ln+transpose1 merged; qk_prep+vtrans merged; attn+transpose2 merged.

#define DEV static __device__ __forceinline__

typedef __attribute__((ext_vector_type(4))) float f32x4;
typedef __attribute__((ext_vector_type(16))) float f32x16;
typedef __attribute__((ext_vector_type(8))) short s8v;   // 8 x bf16 (4 VGPRs)

DEV unsigned short f2bf(float f) {
  union { float f; unsigned u; } v; v.f = f;
  unsigned r = v.u + 0x7fffu + ((v.u >> 16) & 1u);
  return (unsigned short)(r >> 16);
}
DEV float bf2f(unsigned short b) {
  union { unsigned u; float f; } v; v.u = ((unsigned)b) << 16; return v.f;
}
DEV unsigned pk2bf(float a, float b) {
  union { __hip_bfloat162 h; unsigned u; } v;
  v.h = __float22bfloat162_rn(make_float2(a, b));
  return v.u;
}

DEV void gl_lds16(const void* g, void* l) {
  __builtin_amdgcn_global_load_lds(
      (const __attribute__((address_space(1))) unsigned int*)(uintptr_t)g,
      (__attribute__((address_space(3))) unsigned int*)(uint32_t)(uintptr_t)l,
      16, 0, 0);
}

// ---------------- mod = silu(vec) @ mod_w + mod_b (split-K GEMV) ----------------
__global__ __launch_bounds__(256) void modvec_partial(
    const float* __restrict__ vec, const float* __restrict__ mod_w, float* __restrict__ part) {
  __shared__ float s[384];
  const int tid = threadIdx.x;
  const int i0 = blockIdx.y * 384;
  for (int i = tid; i < 384; i += 256) {
    float v = vec[i0 + i];
    s[i] = v / (1.f + __expf(-v));
  }
  __syncthreads();
  const int j = blockIdx.x * 256 + tid;
  float acc = 0.f;
#pragma unroll 8
  for (int i = 0; i < 384; ++i) acc += s[i] * mod_w[(size_t)(i0 + i) * 9216 + j];
  part[(size_t)blockIdx.y * 9216 + j] = acc;
}

__global__ __launch_bounds__(256) void modvec_reduce(
    const float* __restrict__ part, const float* __restrict__ mod_b, float* __restrict__ mod) {
  const int j = blockIdx.x * 256 + threadIdx.x;
  float a = mod_b[j];
#pragma unroll
  for (int y = 0; y < 8; ++y) a += part[(size_t)y * 9216 + j];
  mod[j] = a;
}

// ---------------- merged: LN+mod (blocks 0..2047) + lin1_w transpose ----------------
__global__ __launch_bounds__(256) void ln_tr1_kernel(
    const float* __restrict__ img, const float* __restrict__ mod, unsigned short* __restrict__ x,
    const float* __restrict__ W1, unsigned short* __restrict__ W1t) {
  __shared__ float t[64][65];
  const int bx = blockIdx.x, tid = threadIdx.x;

  if (bx >= 2048) {  // ---- transpose lin1_w (3072,21504) f32 -> (21504,3072) bf16
    const int tb = bx - 2048;
    const int k0 = (tb % 48) * 64, n0 = (tb / 48) * 64;
#pragma unroll
    for (int it = 0; it < 4; ++it) {
      const int k = it * 16 + (tid >> 4), c4 = (tid & 15) * 4;
      f32x4 v = *(const f32x4*)&W1[(size_t)(k0 + k) * 21504 + n0 + c4];
      t[k][c4] = v[0]; t[k][c4 + 1] = v[1]; t[k][c4 + 2] = v[2]; t[k][c4 + 3] = v[3];
    }
    __syncthreads();
#pragma unroll
    for (int it = 0; it < 2; ++it) {
      const int idx = it * 256 + tid;
      const int n = idx >> 3, k8 = (idx & 7) * 8;
      s8v o;
#pragma unroll
      for (int e = 0; e < 8; ++e) o[e] = (short)f2bf(t[k8 + e][n]);
      *(s8v*)&W1t[(size_t)(n0 + n) * 3072 + k0 + k8] = o;
    }
    return;
  }

  // ---- x = (1+scale)*LN(img) + shift -> bf16 ----
  const int l = bx;
  const int wave = tid >> 6;
  const f32x4* row = (const f32x4*)(img + (size_t)l * 3072);
  f32x4 v[3];
  float s = 0.f, s2 = 0.f;
#pragma unroll
  for (int i = 0; i < 3; ++i) {
    v[i] = row[tid + i * 256];
#pragma unroll
    for (int c = 0; c < 4; ++c) { s += v[i][c]; s2 += v[i][c] * v[i][c]; }
  }
#pragma unroll
  for (int m = 1; m < 64; m <<= 1) { s += __shfl_xor(s, m); s2 += __shfl_xor(s2, m); }
  if ((tid & 63) == 0) { t[0][wave] = s; t[0][4 + wave] = s2; }
  __syncthreads();
  s = t[0][0] + t[0][1] + t[0][2] + t[0][3];
  s2 = t[0][4] + t[0][5] + t[0][6] + t[0][7];
  const float mu = s * (1.f / 3072.f);
  const float var = s2 * (1.f / 3072.f) - mu * mu;
  const float inv = rsqrtf(var + 1e-6f);
#pragma unroll
  for (int i = 0; i < 3; ++i) {
    int d0 = (tid + i * 256) * 4;
    unsigned short o[4];
#pragma unroll
    for (int c = 0; c < 4; ++c) {
      int d = d0 + c;
      float val = (1.f + mod[3072 + d]) * ((v[i][c] - mu) * inv) + mod[d];
      o[c] = f2bf(val);
    }
    *(uint2*)(x + (size_t)l * 3072 + d0) =
        make_uint2(o[0] | ((unsigned)o[1] << 16), o[2] | ((unsigned)o[3] << 16));
  }
}

// ---------------- 256x256 bf16 MFMA GEMM (R13 schedule, frozen) ----------------
// Stage pattern per tile t (p=t&1, pn=p^1): P0: A1(pn,t+1); P1: A0(p,t+2);
// P2: B0(p,t+2); P3: B1(p,t+2). Reads one phase ahead inside MFMA windows;
// compiler orders within the window. Counted vmcnt {-,8,8,6}.
// EPI=0 (gemm1): +bias; cols<9216 -> proj; else gelu -> A2 (stride 15360).
// EPI=2 (gemm2): bf16 split-K partials, kOff = bz*nTile*64.
template <int EPI>
__global__ __launch_bounds__(512, 2) void gemm256_kernel(
    const unsigned short* __restrict__ A, const unsigned short* __restrict__ Bt,
    const float* __restrict__ bias, void* __restrict__ Cout, void* __restrict__ Cout2,
    int K, int N, int nTile, int nBN) {
  __shared__ unsigned short lds[65536];  // 128 KiB
  const int tid = threadIdx.x;
  const int lane = tid & 63, w = tid >> 6;
  const int wm = w >> 2, wn = w & 3;
  const int l15 = lane & 15, l4 = lane >> 4;

  int bid = blockIdx.x;
  const int nwg = gridDim.x;
  bid = (bid & 7) * (nwg >> 3) + (bid >> 3);   // XCD-aware swizzle (grid % 8 == 0)
  const int bz = bid / (nBN << 3);
  const int rem = bid - bz * (nBN << 3);
  const int m0 = (rem & 7) << 8;
  const int n0 = (rem >> 3) << 8;
  const int kOff = bz * nTile * 64;

  const int sr = (w << 3) + (lane >> 3);
  const int skc = ((lane & 7) ^ (sr & 7)) << 3;
  const size_t aBase = (size_t)m0 * K + kOff;
  const size_t bBase = (size_t)n0 * K + kOff;

  const int xs0 = (l4 ^ (l15 & 7)) << 3;
  const int xs1 = ((4 + l4) ^ (l15 & 7)) << 3;
  int aRow[4], bRow[2];
#pragma unroll
  for (int i = 0; i < 4; ++i) aRow[i] = (wm * 64 + i * 16 + l15) * 64;
#pragma unroll
  for (int j = 0; j < 2; ++j) bRow[j] = (wn * 32 + j * 16 + l15) * 64;

  f32x4 acc[2][2][4][2];
#pragma unroll
  for (int mq = 0; mq < 2; ++mq)
#pragma unroll
    for (int nq = 0; nq < 2; ++nq)
#pragma unroll
      for (int i = 0; i < 4; ++i)
#pragma unroll
        for (int j = 0; j < 2; ++j) acc[mq][nq][i][j] = (f32x4){0.f, 0.f, 0.f, 0.f};

#define STAGE(op, h, par, kt)                                                        \
  do {                                                                               \
    const unsigned short* _s = (op) ? Bt : A;                                        \
    const size_t _b = (op) ? bBase : aBase;                                          \
    unsigned short* _d = &lds[((par) << 15) + ((op) << 14) + ((h) << 13) + (w << 9)];\
    gl_lds16(_s + _b + (size_t)((h) * 128 + sr) * K + (kt) * 64 + skc, _d);          \
    gl_lds16(_s + _b + (size_t)((h) * 128 + 64 + sr) * K + (kt) * 64 + skc, _d + 4096);\
  } while (0)

#define FRAGP(op, h, par, rowoff, xsv) \
  (*(const s8v*)&lds[((par) << 15) + ((op) << 14) + ((h) << 13) + (rowoff) + (xsv)])

#define RD_A(dst, h, par)                                                       \
  _Pragma("unroll") for (int i = 0; i < 4; ++i) {                               \
    dst[i][0] = FRAGP(0, h, par, aRow[i], xs0);                                 \
    dst[i][1] = FRAGP(0, h, par, aRow[i], xs1);                                 \
  }

#define RD_B(dst, h, par)                                                       \
  _Pragma("unroll") for (int j = 0; j < 2; ++j) {                               \
    dst[j][0] = FRAGP(1, h, par, bRow[j], xs0);                                 \
    dst[j][1] = FRAGP(1, h, par, bRow[j], xs1);                                 \
  }

#define PH_OPEN()                                           \
  __builtin_amdgcn_s_barrier();                             \
  asm volatile("s_waitcnt lgkmcnt(0)" ::: "memory");        \
  __builtin_amdgcn_sched_barrier(0);                        \
  __builtin_amdgcn_s_setprio(1)

#define PH_CLOSE()                                          \
  __builtin_amdgcn_sched_barrier(0);                        \
  __builtin_amdgcn_s_setprio(0);                            \
  __builtin_amdgcn_s_barrier()

#define PH_CLOSE_VM(NN)                                     \
  __builtin_amdgcn_sched_barrier(0);                        \
  __builtin_amdgcn_s_setprio(0);                            \
  asm volatile("s_waitcnt vmcnt(" #NN ")" ::: "memory");    \
  __builtin_amdgcn_s_barrier()

#define MFMA_QUAD(mq, nq, av, bv)                                                      \
  _Pragma("unroll") for (int i = 0; i < 4; ++i) _Pragma("unroll") for (int j = 0; j < 2; ++j) { \
    acc[mq][nq][i][j] =                                                                \
        __builtin_amdgcn_mfma_f32_16x16x32_bf16(av[i][0], bv[j][0], acc[mq][nq][i][j], 0, 0, 0); \
    acc[mq][nq][i][j] =                                                                \
        __builtin_amdgcn_mfma_f32_16x16x32_bf16(av[i][1], bv[j][1], acc[mq][nq][i][j], 0, 0, 0); \
  }

  STAGE(0, 0, 0, 0); STAGE(1, 0, 0, 0); STAGE(1, 1, 0, 0); STAGE(0, 1, 0, 0);
  {
    const int k1 = (nTile > 1) ? 1 : 0;
    STAGE(0, 0, 1, k1); STAGE(1, 0, 1, k1); STAGE(1, 1, 1, k1);
  }
  asm volatile("s_waitcnt vmcnt(6)" ::: "memory");
  __builtin_amdgcn_s_barrier();

  s8v aA[4][2], aB[4][2], b0[2][2], b1[2][2];
  RD_A(aA, 0, 0);
  RD_B(b0, 0, 0);

#pragma unroll 2
  for (int t = 0; t < nTile; ++t) {
    const int p = t & 1, pn = p ^ 1;
    const int kt1 = (t + 1 < nTile) ? t + 1 : 0;
    const int kt2 = (t + 2 < nTile) ? t + 2 : 0;
    // ---- P0: read b1<=B1(p,t); MFMA q(0,0); stage A1(pn,t+1) ----
    STAGE(0, 1, pn, kt1);
    PH_OPEN();
    RD_B(b1, 1, p);
    MFMA_QUAD(0, 0, aA, b0);
    PH_CLOSE();
    // ---- P1: read aB<=A1(p,t); MFMA q(0,1); stage A0(p,t+2) ----
    STAGE(0, 0, p, kt2);
    PH_OPEN();
    RD_A(aB, 1, p);
    MFMA_QUAD(0, 1, aA, b1);
    PH_CLOSE_VM(8);
    // ---- P2: read aA<=A0(pn,t+1); MFMA q(1,0); stage B0(p,t+2) ----
    STAGE(1, 0, p, kt2);
    PH_OPEN();
    RD_A(aA, 0, pn);
    MFMA_QUAD(1, 0, aB, b0);
    PH_CLOSE_VM(8);
    // ---- P3: read b0<=B0(pn,t+1); MFMA q(1,1); stage B1(p,t+2) ----
    STAGE(1, 1, p, kt2);
    PH_OPEN();
    RD_B(b0, 0, pn);
    MFMA_QUAD(1, 1, aB, b1);
    PH_CLOSE_VM(6);
  }

  // Drain ALL outstanding DMA + LDS reads before epilogue/exit (Round 3 lesson).
  asm volatile("s_waitcnt vmcnt(0) lgkmcnt(0)" ::: "memory");
  __builtin_amdgcn_s_barrier();

  if (EPI == 0) {
    if (n0 < 9216) {  // block-uniform: qkv -> proj (stride 9216)
#pragma unroll
      for (int mq = 0; mq < 2; ++mq)
#pragma unroll
        for (int nq = 0; nq < 2; ++nq)
#pragma unroll
          for (int j = 0; j < 2; ++j) {
            const int col = n0 + nq * 128 + wn * 32 + j * 16 + l15;
            const float bj = bias[col];
#pragma unroll
            for (int i = 0; i < 4; ++i) {
              const int row0 = m0 + mq * 128 + wm * 64 + i * 16 + (l4 << 2);
#pragma unroll
              for (int r = 0; r < 4; ++r)
                ((unsigned short*)Cout)[(size_t)(row0 + r) * 9216 + col] =
                    f2bf(acc[mq][nq][i][j][r] + bj);
            }
          }
    } else {  // block-uniform: mlp -> gelu -> A2 (stride 15360, col-6144)
#pragma unroll
      for (int mq = 0; mq < 2; ++mq)
#pragma unroll
        for (int nq = 0; nq < 2; ++nq)
#pragma unroll
          for (int j = 0; j < 2; ++j) {
            const int col = n0 + nq * 128 + wn * 32 + j * 16 + l15;
            const float bj = bias[col];
#pragma unroll
            for (int i = 0; i < 4; ++i) {
              const int row0 = m0 + mq * 128 + wm * 64 + i * 16 + (l4 << 2);
#pragma unroll
              for (int r = 0; r < 4; ++r) {
                const float v = acc[mq][nq][i][j][r] + bj;
                const float y = 0.7978845608f * (v + 0.044715f * v * v * v);
                const float ex = exp2f(2.8853900818f * y);
                const float g = v - v * __builtin_amdgcn_rcpf(ex + 1.f);
                ((unsigned short*)Cout2)[(size_t)(row0 + r) * 15360 + (col - 6144)] = f2bf(g);
              }
            }
          }
    }
  } else {  // bf16 split-K partials
#pragma unroll
    for (int mq = 0; mq < 2; ++mq)
#pragma unroll
      for (int nq = 0; nq < 2; ++nq)
#pragma unroll
        for (int j = 0; j < 2; ++j) {
          const int col = n0 + nq * 128 + wn * 32 + j * 16 + l15;
#pragma unroll
          for (int i = 0; i < 4; ++i) {
            const int row0 = m0 + mq * 128 + wm * 64 + i * 16 + (l4 << 2);
#pragma unroll
            for (int r = 0; r < 4; ++r)
              ((unsigned short*)Cout)[(size_t)bz * 2048 * N + (size_t)(row0 + r) * N + col] =
                  f2bf(acc[mq][nq][i][j][r]);
          }
        }
  }
#undef STAGE
#undef FRAGP
#undef RD_A
#undef RD_B
#undef PH_OPEN
#undef PH_CLOSE
#undef PH_CLOSE_VM
#undef MFMA_QUAD
}

// ---------------- gemm2 split-K(8, bf16 partials) reduce + gate + residual ----------------
__global__ __launch_bounds__(256) void reduce2_kernel(
    const unsigned short* __restrict__ part, const float* __restrict__ img,
    const float* __restrict__ mod, const float* __restrict__ bias, float* __restrict__ out) {
  const size_t idx = ((size_t)blockIdx.x * 256 + threadIdx.x) * 4;
  const int col = (int)(idx % 3072);
  float s[4] = {0.f, 0.f, 0.f, 0.f};
#pragma unroll
  for (int z = 0; z < 8; ++z) {
    const uint2 pv = *(const uint2*)(part + (size_t)z * 6291456 + idx);
    s[0] += bf2f((unsigned short)(pv.x & 0xffff));
    s[1] += bf2f((unsigned short)(pv.x >> 16));
    s[2] += bf2f((unsigned short)(pv.y & 0xffff));
    s[3] += bf2f((unsigned short)(pv.y >> 16));
  }
  f32x4 im = *(const f32x4*)(img + idx);
  f32x4 o;
#pragma unroll
  for (int e = 0; e < 4; ++e)
    o[e] = im[e] + mod[6144 + col + e] * (s[e] + bias[col + e]);
  *(f32x4*)(out + idx) = o;
}

// ---------------- merged: RMSnorm(q,k)+RoPE (0..2047) + V transpose ----------------
DEV void qk_one(const unsigned short* src, const float* sc, const f32x4 pe4, float extra,
                unsigned short* dst, int lane) {
  unsigned xx = *(const unsigned*)(src + 2 * lane);
  float x0 = bf2f((unsigned short)(xx & 0xffff));
  float x1 = bf2f((unsigned short)(xx >> 16));
  float ss = x0 * x0 + x1 * x1;
#pragma unroll
  for (int m = 1; m < 64; m <<= 1) ss += __shfl_xor(ss, m);
  const float inv = rsqrtf(ss * (1.f / 128.f) + 1e-6f);
  x0 *= inv * sc[2 * lane];
  x1 *= inv * sc[2 * lane + 1];
  float o0 = (pe4.x * x0 + pe4.y * x1) * extra;
  float o1 = (pe4.z * x0 + pe4.w * x1) * extra;
  *(unsigned*)(dst + 2 * lane) = (unsigned)f2bf(o0) | ((unsigned)f2bf(o1) << 16);
}

__global__ __launch_bounds__(256) void qkv_prep_kernel(
    const unsigned short* __restrict__ proj, const float* __restrict__ pe,
    const float* __restrict__ q_scale, const float* __restrict__ k_scale,
    unsigned short* __restrict__ qr, unsigned short* __restrict__ kr,
    unsigned short* __restrict__ vt) {
  __shared__ unsigned short t[128][136];
  const int bx = blockIdx.x, tid = threadIdx.x;

  if (bx >= 2048) {  // ---- V transpose: proj v-cols -> vt[h*128+dh][l] ----
    const int tb = bx - 2048;
    const int h = tb >> 4, l0 = (tb & 15) * 128;
    const int row = tid >> 1, half = tid & 1;
    const unsigned short* src = proj + (size_t)(l0 + row) * 9216 + 6144 + h * 128 + half * 64;
#pragma unroll
    for (int cc = 0; cc < 8; ++cc)
      *(s8v*)&t[row][half * 64 + cc * 8] = *(const s8v*)(src + cc * 8);
    __syncthreads();
    const int dh = tid >> 1;
    unsigned short* dst = vt + ((size_t)h * 128 + dh) * 2048 + l0 + half * 64;
#pragma unroll
    for (int lc = 0; lc < 8; ++lc) {
      s8v o;
#pragma unroll
      for (int e = 0; e < 8; ++e) o[e] = (short)t[half * 64 + lc * 8 + e][dh];
      *(s8v*)(dst + lc * 8) = o;
    }
    return;
  }

  const int l = bx;
  const int lane = tid & 63, wave = tid >> 6;
  const unsigned short* row = proj + (size_t)l * 9216;
  const f32x4 pe4 = *(const f32x4*)(pe + ((size_t)l * 64 + lane) * 4);
  const float qsc = 0.12751743761f;  // Dh^-0.5 * log2(e) folded into q
#pragma unroll
  for (int hh = 0; hh < 6; ++hh) {
    const int h = wave + hh * 4;
    qk_one(row + h * 128, q_scale, pe4, qsc, qr + ((size_t)h * 2048 + l) * 128, lane);
    qk_one(row + 3072 + h * 128, k_scale, pe4, 1.f, kr + ((size_t)h * 2048 + l) * 128, lane);
  }
}

// ---------------- flash attention (blocks 0..383) + lin2_w transpose (384..) ----
__global__ __launch_bounds__(256) void attn_kernel(
    const unsigned short* __restrict__ qr, const unsigned short* __restrict__ kr,
    const unsigned short* __restrict__ vt, unsigned short* __restrict__ A2,
    const float* __restrict__ W2, unsigned short* __restrict__ W2t) {
  __shared__ char lds[65536];
  const int bx = blockIdx.x;
  const int tid = threadIdx.x;

  if (bx >= 384) {
    const int tb = bx - 384;
    const int k0 = (tb % 240) * 64, n0 = (tb / 240) * 64;
    float (*t)[65] = (float(*)[65])lds;
#pragma unroll
    for (int it = 0; it < 4; ++it) {
      const int k = it * 16 + (tid >> 4), c4 = (tid & 15) * 4;
      f32x4 v = *(const f32x4*)&W2[(size_t)(k0 + k) * 3072 + n0 + c4];
      t[k][c4] = v[0]; t[k][c4 + 1] = v[1]; t[k][c4 + 2] = v[2]; t[k][c4 + 3] = v[3];
    }
    __syncthreads();
#pragma unroll
    for (int it = 0; it < 2; ++it) {
      const int idx = it * 256 + tid;
      const int n = idx >> 3, k8 = (idx & 7) * 8;
      s8v o;
#pragma unroll
      for (int e = 0; e < 8; ++e) o[e] = (short)f2bf(t[k8 + e][n]);
      *(s8v*)&W2t[(size_t)(n0 + n) * 15360 + k0 + k8] = o;
    }
    return;
  }

  const int lane = tid & 63, w = tid >> 6;
  const int l31 = lane & 31, hi = lane >> 5;
  const int h = bx >> 4;
  const int q0 = (bx & 15) * 128 + w * 32;
  const int q = q0 + l31;

  s8v qf[8];
  {
    const unsigned short* qb = qr + ((size_t)h * 2048 + q) * 128 + hi * 8;
#pragma unroll
    for (int ks = 0; ks < 8; ++ks) qf[ks] = *(const s8v*)(qb + ks * 16);
  }

  int koff[4], voff[4];
#pragma unroll
  for (int c = 0; c < 4; ++c) {
    const int ob = (w * 4 + c) * 1024 + lane * 16;
    const int row = ob >> 8;
    const int sl = (ob >> 4) & 15;
    const int ssl = sl ^ (row & 15);
    koff[c] = row * 128 + ssl * 8;
    const int dh = row * 2 + (ssl >> 3);
    voff[c] = dh * 2048 + (ssl & 7) * 8;
  }
  const unsigned short* krH = kr + (size_t)h * 2048 * 128;
  const unsigned short* vtH = vt + (size_t)h * 128 * 2048;

  f32x16 oacc[4];
#pragma unroll
  for (int rf = 0; rf < 4; ++rf)
#pragma unroll
    for (int e = 0; e < 16; ++e) oacc[rf][e] = 0.f;
  float m = -3e38f, l = 0.f;

#define ATT_STAGE(t)                                                        \
  do {                                                                      \
    char* kb_ = lds + ((t) & 1) * 32768;                                    \
    char* vb_ = kb_ + 16384;                                                \
    _Pragma("unroll") for (int c = 0; c < 4; ++c) {                         \
      gl_lds16(krH + (size_t)(t) * 8192 + koff[c], kb_ + (w * 4 + c) * 1024); \
      gl_lds16(vtH + (size_t)(t) * 64 + voff[c], vb_ + (w * 4 + c) * 1024);   \
    }                                                                       \
  } while (0)

  ATT_STAGE(0);
  __syncthreads();

  for (int t = 0; t < 32; ++t) {
    if (t + 1 < 32) ATT_STAGE(t + 1);
    char* kb = lds + (t & 1) * 32768;
    char* vb = kb + 16384;

    f32x16 st[2];
#pragma unroll
    for (int rf = 0; rf < 2; ++rf)
#pragma unroll
      for (int e = 0; e < 16; ++e) st[rf][e] = 0.f;
#pragma unroll
    for (int ks = 0; ks < 8; ++ks)
#pragma unroll
      for (int rf = 0; rf < 2; ++rf) {
        const int kvr = rf * 32 + l31;
        s8v kf = *(const s8v*)(kb + kvr * 256 + (((ks * 2 + hi) ^ (kvr & 15)) << 4));
        st[rf] = __builtin_amdgcn_mfma_f32_32x32x16_bf16(kf, qf[ks], st[rf], 0, 0, 0);
      }

    float pm = st[0][0];
#pragma unroll
    for (int rf = 0; rf < 2; ++rf)
#pragma unroll
      for (int e = 0; e < 16; ++e) pm = fmaxf(pm, st[rf][e]);
    pm = fmaxf(pm, __shfl_xor(pm, 32));
    if (__any(pm - m > 11.5f)) {   // defer-max (T13, log2 units)
      const float mn = fmaxf(m, pm);
      const float rs = exp2f(m - mn);
      l *= rs;
#pragma unroll
      for (int rf = 0; rf < 4; ++rf)
#pragma unroll
        for (int e = 0; e < 16; ++e) oacc[rf][e] *= rs;
      m = mn;
    }
    unsigned P2[16];
#pragma unroll
    for (int rb = 0; rb < 2; ++rb)
#pragma unroll
      for (int g = 0; g < 4; ++g) {
        const float e0 = exp2f(st[rb][4 * g + 0] - m);
        const float e1 = exp2f(st[rb][4 * g + 1] - m);
        const float e2 = exp2f(st[rb][4 * g + 2] - m);
        const float e3 = exp2f(st[rb][4 * g + 3] - m);
        l += (e0 + e1) + (e2 + e3);
        P2[rb * 8 + g * 2 + 0] = pk2bf(e0, e1);
        P2[rb * 8 + g * 2 + 1] = pk2bf(e2, e3);
      }

#pragma unroll
    for (int ks = 0; ks < 4; ++ks) {
      const int iA = ((2 * ks) >> 2) * 8 + ((2 * ks) & 3) * 2;
      const int iB = ((2 * ks + 1) >> 2) * 8 + ((2 * ks + 1) & 3) * 2;
      const unsigned s0 = hi ? P2[iA] : P2[iB];
      const unsigned s1 = hi ? P2[iA + 1] : P2[iB + 1];
      const unsigned r0 = (unsigned)__shfl_xor((int)s0, 32);
      const unsigned r1 = (unsigned)__shfl_xor((int)s1, 32);
      const unsigned o0 = hi ? P2[iB] : P2[iA];
      const unsigned o1 = hi ? P2[iB + 1] : P2[iA + 1];
      union { unsigned u[4]; s8v v; } pf;
      pf.u[0] = hi ? r0 : o0;
      pf.u[1] = hi ? r1 : o1;
      pf.u[2] = hi ? o0 : r0;
      pf.u[3] = hi ? o1 : r1;
#pragma unroll
      for (int rf = 0; rf < 4; ++rf) {
        const int dh = rf * 32 + l31, r = dh >> 1;
        const int sl = ((dh & 1) << 3) + ks * 2 + hi;
        s8v vf = *(const s8v*)(vb + r * 256 + ((sl ^ (r & 15)) << 4));
        oacc[rf] = __builtin_amdgcn_mfma_f32_32x32x16_bf16(vf, pf.v, oacc[rf], 0, 0, 0);
      }
    }
    __syncthreads();
  }

  const float lf = l + __shfl_xor(l, 32);
  const float inv = 1.f / lf;
  char* ep = lds + w * 8448;
#pragma unroll
  for (int rf = 0; rf < 4; ++rf)
#pragma unroll
    for (int g = 0; g < 4; ++g) {
      const unsigned u0 = pk2bf(oacc[rf][4 * g + 0] * inv, oacc[rf][4 * g + 1] * inv);
      const unsigned u1 = pk2bf(oacc[rf][4 * g + 2] * inv, oacc[rf][4 * g + 3] * inv);
      *(uint2*)(ep + l31 * 264 + rf * 64 + g * 16 + hi * 8) = make_uint2(u0, u1);
    }
  __syncthreads();
  const int c = lane & 15, l4b = lane >> 4;
#pragma unroll
  for (int pass = 0; pass < 8; ++pass) {
    const int qq = pass * 4 + l4b;
    const uint2 a2 = *(const uint2*)(ep + qq * 264 + c * 16);
    const uint2 b2 = *(const uint2*)(ep + qq * 264 + c * 16 + 8);
    *(uint4*)(A2 + (size_t)(q0 + qq) * 15360 + h * 128 + c * 8) =
        make_uint4(a2.x, a2.y, b2.x, b2.y);
  }
#undef ATT_STAGE
}

// ---------------- launch ----------------
extern "C" void kernel_launch(void* const* d_in, const int* in_sizes, int n_in,
                              void* d_out, int out_size, void* d_ws, size_t ws_size,
                              hipStream_t stream) {
  (void)in_sizes; (void)n_in; (void)out_size; (void)ws_size;
  const float* img    = (const float*)d_in[0];
  const float* vec    = (const float*)d_in[1];
  const float* pe     = (const float*)d_in[2];
  const float* mod_w  = (const float*)d_in[3];
  const float* mod_b  = (const float*)d_in[4];
  const float* lin1_w = (const float*)d_in[5];
  const float* lin1_b = (const float*)d_in[6];
  const float* lin2_w = (const float*)d_in[7];
  const float* lin2_b = (const float*)d_in[8];
  const float* q_s    = (const float*)d_in[9];
  const float* k_s    = (const float*)d_in[10];
  float* out = (float*)d_out;

  char* ws = (char*)d_ws;
  size_t off = 0;
  auto alloc = [&](size_t b) { size_t p = off; off += (b + 255) & ~(size_t)255; return p; };
  float* part          = (float*)(ws + alloc((size_t)8 * 9216 * 4));
  float* mod           = (float*)(ws + alloc((size_t)9216 * 4));
  unsigned short* x    = (unsigned short*)(ws + alloc((size_t)2048 * 3072 * 2));
  unsigned short* wT   = (unsigned short*)(ws + alloc((size_t)21504 * 3072 * 2));  // w1t then w2t
  unsigned short* proj = (unsigned short*)(ws + alloc((size_t)2048 * 21504 * 2));  // qkv uses 9216 stride
  unsigned short* qr   = (unsigned short*)(ws + alloc((size_t)24 * 2048 * 128 * 2));
  unsigned short* kr   = (unsigned short*)(ws + alloc((size_t)24 * 2048 * 128 * 2));
  unsigned short* vt   = (unsigned short*)(ws + alloc((size_t)24 * 128 * 2048 * 2));
  unsigned short* A2   = (unsigned short*)(ws + alloc((size_t)2048 * 15360 * 2));
  // gemm2 split-K(8) bf16 partials: 8 x 12,582,912 B = 100.7 MB, fits in the
  // dead contiguous proj+qr+kr+vt region (125.8 MB).
  unsigned short* p2buf = (unsigned short*)proj;

  modvec_partial<<<dim3(36, 8), 256, 0, stream>>>(vec, mod_w, part);
  modvec_reduce<<<36, 256, 0, stream>>>(part, mod_b, mod);
  // merged: LN (2048 blocks) + lin1_w transpose (16128 blocks)
  ln_tr1_kernel<<<2048 + 16128, 256, 0, stream>>>(img, mod, x, lin1_w, wT);
  gemm256_kernel<0><<<672, 512, 0, stream>>>(x, wT, lin1_b, proj, A2, 3072, 21504, 48, 84);
  // merged: qk norm+rope (2048 blocks) + V transpose (384 blocks)
  qkv_prep_kernel<<<2048 + 384, 256, 0, stream>>>(proj, pe, q_s, k_s, qr, kr, vt);
  // merged: attn (384 blocks) + lin2_w transpose (11520 blocks)
  attn_kernel<<<384 + 11520, 256, 0, stream>>>(qr, kr, vt, A2, lin2_w, wT);
  // gemm2: split-K=8, 768 blocks = exactly 3 full CU rounds
  gemm256_kernel<2><<<768, 512, 0, stream>>>(A2, wT, nullptr, p2buf, nullptr, 15360, 3072, 30, 12);
  reduce2_kernel<<<6144, 256, 0, stream>>>(p2buf, img, mod, lin2_b, out);
}

// Round 17
// 769.289 us; speedup vs baseline: 1.0267x; 1.0267x over previous
//
#include <hip/hip_runtime.h>
#include <hip/hip_bf16.h>
#include <stdint.h>

// SingleStreamBlock fused pipeline, all-bf16 MFMA datapath.
// GEMMs: 256x256 4-phase/K-tile (R13 schedule, FROZEN). gemm1 fuses gelu;
// gemm2 split-K=5 bf16 partials (best measured). ln+transpose1 merged;
// qk_prep+vtrans merged; attn+transpose2 merged (2 tiles per rider block).

#define DEV static __device__ __forceinline__

typedef __attribute__((ext_vector_type(4))) float f32x4;
typedef __attribute__((ext_vector_type(16))) float f32x16;
typedef __attribute__((ext_vector_type(8))) short s8v;   // 8 x bf16 (4 VGPRs)

DEV unsigned short f2bf(float f) {
  union { float f; unsigned u; } v; v.f = f;
  unsigned r = v.u + 0x7fffu + ((v.u >> 16) & 1u);
  return (unsigned short)(r >> 16);
}
DEV float bf2f(unsigned short b) {
  union { unsigned u; float f; } v; v.u = ((unsigned)b) << 16; return v.f;
}
DEV unsigned pk2bf(float a, float b) {
  union { __hip_bfloat162 h; unsigned u; } v;
  v.h = __float22bfloat162_rn(make_float2(a, b));
  return v.u;
}

DEV void gl_lds16(const void* g, void* l) {
  __builtin_amdgcn_global_load_lds(
      (const __attribute__((address_space(1))) unsigned int*)(uintptr_t)g,
      (__attribute__((address_space(3))) unsigned int*)(uint32_t)(uintptr_t)l,
      16, 0, 0);
}

// ---------------- mod = silu(vec) @ mod_w + mod_b (split-K GEMV) ----------------
__global__ __launch_bounds__(256) void modvec_partial(
    const float* __restrict__ vec, const float* __restrict__ mod_w, float* __restrict__ part) {
  __shared__ float s[384];
  const int tid = threadIdx.x;
  const int i0 = blockIdx.y * 384;
  for (int i = tid; i < 384; i += 256) {
    float v = vec[i0 + i];
    s[i] = v / (1.f + __expf(-v));
  }
  __syncthreads();
  const int j = blockIdx.x * 256 + tid;
  float acc = 0.f;
#pragma unroll 8
  for (int i = 0; i < 384; ++i) acc += s[i] * mod_w[(size_t)(i0 + i) * 9216 + j];
  part[(size_t)blockIdx.y * 9216 + j] = acc;
}

__global__ __launch_bounds__(256) void modvec_reduce(
    const float* __restrict__ part, const float* __restrict__ mod_b, float* __restrict__ mod) {
  const int j = blockIdx.x * 256 + threadIdx.x;
  float a = mod_b[j];
#pragma unroll
  for (int y = 0; y < 8; ++y) a += part[(size_t)y * 9216 + j];
  mod[j] = a;
}

// ---------------- merged: LN+mod (blocks 0..2047) + lin1_w transpose ----------------
__global__ __launch_bounds__(256) void ln_tr1_kernel(
    const float* __restrict__ img, const float* __restrict__ mod, unsigned short* __restrict__ x,
    const float* __restrict__ W1, unsigned short* __restrict__ W1t) {
  __shared__ float t[64][65];
  const int bx = blockIdx.x, tid = threadIdx.x;

  if (bx >= 2048) {  // ---- transpose lin1_w (3072,21504) f32 -> (21504,3072) bf16
    const int tb = bx - 2048;
    const int k0 = (tb % 48) * 64, n0 = (tb / 48) * 64;
#pragma unroll
    for (int it = 0; it < 4; ++it) {
      const int k = it * 16 + (tid >> 4), c4 = (tid & 15) * 4;
      f32x4 v = *(const f32x4*)&W1[(size_t)(k0 + k) * 21504 + n0 + c4];
      t[k][c4] = v[0]; t[k][c4 + 1] = v[1]; t[k][c4 + 2] = v[2]; t[k][c4 + 3] = v[3];
    }
    __syncthreads();
#pragma unroll
    for (int it = 0; it < 2; ++it) {
      const int idx = it * 256 + tid;
      const int n = idx >> 3, k8 = (idx & 7) * 8;
      s8v o;
#pragma unroll
      for (int e = 0; e < 8; ++e) o[e] = (short)f2bf(t[k8 + e][n]);
      *(s8v*)&W1t[(size_t)(n0 + n) * 3072 + k0 + k8] = o;
    }
    return;
  }

  // ---- x = (1+scale)*LN(img) + shift -> bf16 ----
  const int l = bx;
  const int wave = tid >> 6;
  const f32x4* row = (const f32x4*)(img + (size_t)l * 3072);
  f32x4 v[3];
  float s = 0.f, s2 = 0.f;
#pragma unroll
  for (int i = 0; i < 3; ++i) {
    v[i] = row[tid + i * 256];
#pragma unroll
    for (int c = 0; c < 4; ++c) { s += v[i][c]; s2 += v[i][c] * v[i][c]; }
  }
#pragma unroll
  for (int m = 1; m < 64; m <<= 1) { s += __shfl_xor(s, m); s2 += __shfl_xor(s2, m); }
  if ((tid & 63) == 0) { t[0][wave] = s; t[0][4 + wave] = s2; }
  __syncthreads();
  s = t[0][0] + t[0][1] + t[0][2] + t[0][3];
  s2 = t[0][4] + t[0][5] + t[0][6] + t[0][7];
  const float mu = s * (1.f / 3072.f);
  const float var = s2 * (1.f / 3072.f) - mu * mu;
  const float inv = rsqrtf(var + 1e-6f);
#pragma unroll
  for (int i = 0; i < 3; ++i) {
    int d0 = (tid + i * 256) * 4;
    unsigned short o[4];
#pragma unroll
    for (int c = 0; c < 4; ++c) {
      int d = d0 + c;
      float val = (1.f + mod[3072 + d]) * ((v[i][c] - mu) * inv) + mod[d];
      o[c] = f2bf(val);
    }
    *(uint2*)(x + (size_t)l * 3072 + d0) =
        make_uint2(o[0] | ((unsigned)o[1] << 16), o[2] | ((unsigned)o[3] << 16));
  }
}

// ---------------- 256x256 bf16 MFMA GEMM (R13 schedule, frozen) ----------------
template <int EPI>
__global__ __launch_bounds__(512, 2) void gemm256_kernel(
    const unsigned short* __restrict__ A, const unsigned short* __restrict__ Bt,
    const float* __restrict__ bias, void* __restrict__ Cout, void* __restrict__ Cout2,
    int K, int N, int nTile, int nBN) {
  __shared__ unsigned short lds[65536];  // 128 KiB
  const int tid = threadIdx.x;
  const int lane = tid & 63, w = tid >> 6;
  const int wm = w >> 2, wn = w & 3;
  const int l15 = lane & 15, l4 = lane >> 4;

  int bid = blockIdx.x;
  const int nwg = gridDim.x;
  bid = (bid & 7) * (nwg >> 3) + (bid >> 3);   // XCD-aware swizzle (grid % 8 == 0)
  const int bz = bid / (nBN << 3);
  const int rem = bid - bz * (nBN << 3);
  const int m0 = (rem & 7) << 8;
  const int n0 = (rem >> 3) << 8;
  const int kOff = bz * nTile * 64;

  const int sr = (w << 3) + (lane >> 3);
  const int skc = ((lane & 7) ^ (sr & 7)) << 3;
  const size_t aBase = (size_t)m0 * K + kOff;
  const size_t bBase = (size_t)n0 * K + kOff;

  const int xs0 = (l4 ^ (l15 & 7)) << 3;
  const int xs1 = ((4 + l4) ^ (l15 & 7)) << 3;
  int aRow[4], bRow[2];
#pragma unroll
  for (int i = 0; i < 4; ++i) aRow[i] = (wm * 64 + i * 16 + l15) * 64;
#pragma unroll
  for (int j = 0; j < 2; ++j) bRow[j] = (wn * 32 + j * 16 + l15) * 64;

  f32x4 acc[2][2][4][2];
#pragma unroll
  for (int mq = 0; mq < 2; ++mq)
#pragma unroll
    for (int nq = 0; nq < 2; ++nq)
#pragma unroll
      for (int i = 0; i < 4; ++i)
#pragma unroll
        for (int j = 0; j < 2; ++j) acc[mq][nq][i][j] = (f32x4){0.f, 0.f, 0.f, 0.f};

#define STAGE(op, h, par, kt)                                                        \
  do {                                                                               \
    const unsigned short* _s = (op) ? Bt : A;                                        \
    const size_t _b = (op) ? bBase : aBase;                                          \
    unsigned short* _d = &lds[((par) << 15) + ((op) << 14) + ((h) << 13) + (w << 9)];\
    gl_lds16(_s + _b + (size_t)((h) * 128 + sr) * K + (kt) * 64 + skc, _d);          \
    gl_lds16(_s + _b + (size_t)((h) * 128 + 64 + sr) * K + (kt) * 64 + skc, _d + 4096);\
  } while (0)

#define FRAGP(op, h, par, rowoff, xsv) \
  (*(const s8v*)&lds[((par) << 15) + ((op) << 14) + ((h) << 13) + (rowoff) + (xsv)])

#define RD_A(dst, h, par)                                                       \
  _Pragma("unroll") for (int i = 0; i < 4; ++i) {                               \
    dst[i][0] = FRAGP(0, h, par, aRow[i], xs0);                                 \
    dst[i][1] = FRAGP(0, h, par, aRow[i], xs1);                                 \
  }

#define RD_B(dst, h, par)                                                       \
  _Pragma("unroll") for (int j = 0; j < 2; ++j) {                               \
    dst[j][0] = FRAGP(1, h, par, bRow[j], xs0);                                 \
    dst[j][1] = FRAGP(1, h, par, bRow[j], xs1);                                 \
  }

#define PH_OPEN()                                           \
  __builtin_amdgcn_s_barrier();                             \
  asm volatile("s_waitcnt lgkmcnt(0)" ::: "memory");        \
  __builtin_amdgcn_sched_barrier(0);                        \
  __builtin_amdgcn_s_setprio(1)

#define PH_CLOSE()                                          \
  __builtin_amdgcn_sched_barrier(0);                        \
  __builtin_amdgcn_s_setprio(0);                            \
  __builtin_amdgcn_s_barrier()

#define PH_CLOSE_VM(NN)                                     \
  __builtin_amdgcn_sched_barrier(0);                        \
  __builtin_amdgcn_s_setprio(0);                            \
  asm volatile("s_waitcnt vmcnt(" #NN ")" ::: "memory");    \
  __builtin_amdgcn_s_barrier()

#define MFMA_QUAD(mq, nq, av, bv)                                                      \
  _Pragma("unroll") for (int i = 0; i < 4; ++i) _Pragma("unroll") for (int j = 0; j < 2; ++j) { \
    acc[mq][nq][i][j] =                                                                \
        __builtin_amdgcn_mfma_f32_16x16x32_bf16(av[i][0], bv[j][0], acc[mq][nq][i][j], 0, 0, 0); \
    acc[mq][nq][i][j] =                                                                \
        __builtin_amdgcn_mfma_f32_16x16x32_bf16(av[i][1], bv[j][1], acc[mq][nq][i][j], 0, 0, 0); \
  }

  STAGE(0, 0, 0, 0); STAGE(1, 0, 0, 0); STAGE(1, 1, 0, 0); STAGE(0, 1, 0, 0);
  {
    const int k1 = (nTile > 1) ? 1 : 0;
    STAGE(0, 0, 1, k1); STAGE(1, 0, 1, k1); STAGE(1, 1, 1, k1);
  }
  asm volatile("s_waitcnt vmcnt(6)" ::: "memory");
  __builtin_amdgcn_s_barrier();

  s8v aA[4][2], aB[4][2], b0[2][2], b1[2][2];
  RD_A(aA, 0, 0);
  RD_B(b0, 0, 0);

#pragma unroll 2
  for (int t = 0; t < nTile; ++t) {
    const int p = t & 1, pn = p ^ 1;
    const int kt1 = (t + 1 < nTile) ? t + 1 : 0;
    const int kt2 = (t + 2 < nTile) ? t + 2 : 0;
    // ---- P0: read b1<=B1(p,t); MFMA q(0,0); stage A1(pn,t+1) ----
    STAGE(0, 1, pn, kt1);
    PH_OPEN();
    RD_B(b1, 1, p);
    MFMA_QUAD(0, 0, aA, b0);
    PH_CLOSE();
    // ---- P1: read aB<=A1(p,t); MFMA q(0,1); stage A0(p,t+2) ----
    STAGE(0, 0, p, kt2);
    PH_OPEN();
    RD_A(aB, 1, p);
    MFMA_QUAD(0, 1, aA, b1);
    PH_CLOSE_VM(8);
    // ---- P2: read aA<=A0(pn,t+1); MFMA q(1,0); stage B0(p,t+2) ----
    STAGE(1, 0, p, kt2);
    PH_OPEN();
    RD_A(aA, 0, pn);
    MFMA_QUAD(1, 0, aB, b0);
    PH_CLOSE_VM(8);
    // ---- P3: read b0<=B0(pn,t+1); MFMA q(1,1); stage B1(p,t+2) ----
    STAGE(1, 1, p, kt2);
    PH_OPEN();
    RD_B(b0, 0, pn);
    MFMA_QUAD(1, 1, aB, b1);
    PH_CLOSE_VM(6);
  }

  // Drain ALL outstanding DMA + LDS reads before epilogue/exit (Round 3 lesson).
  asm volatile("s_waitcnt vmcnt(0) lgkmcnt(0)" ::: "memory");
  __builtin_amdgcn_s_barrier();

  if (EPI == 0) {
    if (n0 < 9216) {  // block-uniform: qkv -> proj (stride 9216)
#pragma unroll
      for (int mq = 0; mq < 2; ++mq)
#pragma unroll
        for (int nq = 0; nq < 2; ++nq)
#pragma unroll
          for (int j = 0; j < 2; ++j) {
            const int col = n0 + nq * 128 + wn * 32 + j * 16 + l15;
            const float bj = bias[col];
#pragma unroll
            for (int i = 0; i < 4; ++i) {
              const int row0 = m0 + mq * 128 + wm * 64 + i * 16 + (l4 << 2);
#pragma unroll
              for (int r = 0; r < 4; ++r)
                ((unsigned short*)Cout)[(size_t)(row0 + r) * 9216 + col] =
                    f2bf(acc[mq][nq][i][j][r] + bj);
            }
          }
    } else {  // block-uniform: mlp -> gelu -> A2 (stride 15360, col-6144)
#pragma unroll
      for (int mq = 0; mq < 2; ++mq)
#pragma unroll
        for (int nq = 0; nq < 2; ++nq)
#pragma unroll
          for (int j = 0; j < 2; ++j) {
            const int col = n0 + nq * 128 + wn * 32 + j * 16 + l15;
            const float bj = bias[col];
#pragma unroll
            for (int i = 0; i < 4; ++i) {
              const int row0 = m0 + mq * 128 + wm * 64 + i * 16 + (l4 << 2);
#pragma unroll
              for (int r = 0; r < 4; ++r) {
                const float v = acc[mq][nq][i][j][r] + bj;
                const float y = 0.7978845608f * (v + 0.044715f * v * v * v);
                const float ex = exp2f(2.8853900818f * y);
                const float g = v - v * __builtin_amdgcn_rcpf(ex + 1.f);
                ((unsigned short*)Cout2)[(size_t)(row0 + r) * 15360 + (col - 6144)] = f2bf(g);
              }
            }
          }
    }
  } else {  // bf16 split-K partials
#pragma unroll
    for (int mq = 0; mq < 2; ++mq)
#pragma unroll
      for (int nq = 0; nq < 2; ++nq)
#pragma unroll
        for (int j = 0; j < 2; ++j) {
          const int col = n0 + nq * 128 + wn * 32 + j * 16 + l15;
#pragma unroll
          for (int i = 0; i < 4; ++i) {
            const int row0 = m0 + mq * 128 + wm * 64 + i * 16 + (l4 << 2);
#pragma unroll
            for (int r = 0; r < 4; ++r)
              ((unsigned short*)Cout)[(size_t)bz * 2048 * N + (size_t)(row0 + r) * N + col] =
                  f2bf(acc[mq][nq][i][j][r]);
          }
        }
  }
#undef STAGE
#undef FRAGP
#undef RD_A
#undef RD_B
#undef PH_OPEN
#undef PH_CLOSE
#undef PH_CLOSE_VM
#undef MFMA_QUAD
}

// ---------------- gemm2 split-K(5, bf16 partials) reduce + gate + residual ----------------
// 8 cols/thread, uint4 partial reads. grid 3072.
__global__ __launch_bounds__(256) void reduce2_kernel(
    const unsigned short* __restrict__ part, const float* __restrict__ img,
    const float* __restrict__ mod, const float* __restrict__ bias, float* __restrict__ out) {
  const size_t idx = ((size_t)blockIdx.x * 256 + threadIdx.x) * 8;
  const int col = (int)(idx % 3072);
  float s[8] = {0.f, 0.f, 0.f, 0.f, 0.f, 0.f, 0.f, 0.f};
#pragma unroll
  for (int z = 0; z < 5; ++z) {
    const uint4 pv = *(const uint4*)(part + (size_t)z * 6291456 + idx);
    s[0] += bf2f((unsigned short)(pv.x & 0xffff));
    s[1] += bf2f((unsigned short)(pv.x >> 16));
    s[2] += bf2f((unsigned short)(pv.y & 0xffff));
    s[3] += bf2f((unsigned short)(pv.y >> 16));
    s[4] += bf2f((unsigned short)(pv.z & 0xffff));
    s[5] += bf2f((unsigned short)(pv.z >> 16));
    s[6] += bf2f((unsigned short)(pv.w & 0xffff));
    s[7] += bf2f((unsigned short)(pv.w >> 16));
  }
#pragma unroll
  for (int hh = 0; hh < 2; ++hh) {
    f32x4 im = *(const f32x4*)(img + idx + hh * 4);
    f32x4 o;
#pragma unroll
    for (int e = 0; e < 4; ++e)
      o[e] = im[e] + mod[6144 + col + hh * 4 + e] * (s[hh * 4 + e] + bias[col + hh * 4 + e]);
    *(f32x4*)(out + idx + hh * 4) = o;
  }
}

// ---------------- merged: RMSnorm(q,k)+RoPE (0..2047) + V transpose ----------------
DEV void qk_one(const unsigned short* src, const float* sc, const f32x4 pe4, float extra,
                unsigned short* dst, int lane) {
  unsigned xx = *(const unsigned*)(src + 2 * lane);
  float x0 = bf2f((unsigned short)(xx & 0xffff));
  float x1 = bf2f((unsigned short)(xx >> 16));
  float ss = x0 * x0 + x1 * x1;
#pragma unroll
  for (int m = 1; m < 64; m <<= 1) ss += __shfl_xor(ss, m);
  const float inv = rsqrtf(ss * (1.f / 128.f) + 1e-6f);
  x0 *= inv * sc[2 * lane];
  x1 *= inv * sc[2 * lane + 1];
  float o0 = (pe4.x * x0 + pe4.y * x1) * extra;
  float o1 = (pe4.z * x0 + pe4.w * x1) * extra;
  *(unsigned*)(dst + 2 * lane) = (unsigned)f2bf(o0) | ((unsigned)f2bf(o1) << 16);
}

__global__ __launch_bounds__(256) void qkv_prep_kernel(
    const unsigned short* __restrict__ proj, const float* __restrict__ pe,
    const float* __restrict__ q_scale, const float* __restrict__ k_scale,
    unsigned short* __restrict__ qr, unsigned short* __restrict__ kr,
    unsigned short* __restrict__ vt) {
  __shared__ unsigned short t[128][136];
  const int bx = blockIdx.x, tid = threadIdx.x;

  if (bx >= 2048) {  // ---- V transpose: proj v-cols -> vt[h*128+dh][l] ----
    const int tb = bx - 2048;
    const int h = tb >> 4, l0 = (tb & 15) * 128;
    const int row = tid >> 1, half = tid & 1;
    const unsigned short* src = proj + (size_t)(l0 + row) * 9216 + 6144 + h * 128 + half * 64;
#pragma unroll
    for (int cc = 0; cc < 8; ++cc)
      *(s8v*)&t[row][half * 64 + cc * 8] = *(const s8v*)(src + cc * 8);
    __syncthreads();
    const int dh = tid >> 1;
    unsigned short* dst = vt + ((size_t)h * 128 + dh) * 2048 + l0 + half * 64;
#pragma unroll
    for (int lc = 0; lc < 8; ++lc) {
      s8v o;
#pragma unroll
      for (int e = 0; e < 8; ++e) o[e] = (short)t[half * 64 + lc * 8 + e][dh];
      *(s8v*)(dst + lc * 8) = o;
    }
    return;
  }

  const int l = bx;
  const int lane = tid & 63, wave = tid >> 6;
  const unsigned short* row = proj + (size_t)l * 9216;
  const f32x4 pe4 = *(const f32x4*)(pe + ((size_t)l * 64 + lane) * 4);
  const float qsc = 0.12751743761f;  // Dh^-0.5 * log2(e) folded into q
#pragma unroll
  for (int hh = 0; hh < 6; ++hh) {
    const int h = wave + hh * 4;
    qk_one(row + h * 128, q_scale, pe4, qsc, qr + ((size_t)h * 2048 + l) * 128, lane);
    qk_one(row + 3072 + h * 128, k_scale, pe4, 1.f, kr + ((size_t)h * 2048 + l) * 128, lane);
  }
}

// ---------------- flash attention (blocks 0..383) + lin2_w transpose (384..) ----
// Rider blocks do TWO 64x64 tiles each (5760 riders).
__global__ __launch_bounds__(256) void attn_kernel(
    const unsigned short* __restrict__ qr, const unsigned short* __restrict__ kr,
    const unsigned short* __restrict__ vt, unsigned short* __restrict__ A2,
    const float* __restrict__ W2, unsigned short* __restrict__ W2t) {
  __shared__ char lds[65536];
  const int bx = blockIdx.x;
  const int tid = threadIdx.x;

  if (bx >= 384) {
    const int tb2 = (bx - 384) * 2;
    float (*t)[65] = (float(*)[65])lds;
#pragma unroll
    for (int sub = 0; sub < 2; ++sub) {
      const int tb = tb2 + sub;
      const int k0 = (tb % 240) * 64, n0 = (tb / 240) * 64;
      if (sub) __syncthreads();
#pragma unroll
      for (int it = 0; it < 4; ++it) {
        const int k = it * 16 + (tid >> 4), c4 = (tid & 15) * 4;
        f32x4 v = *(const f32x4*)&W2[(size_t)(k0 + k) * 3072 + n0 + c4];
        t[k][c4] = v[0]; t[k][c4 + 1] = v[1]; t[k][c4 + 2] = v[2]; t[k][c4 + 3] = v[3];
      }
      __syncthreads();
#pragma unroll
      for (int it = 0; it < 2; ++it) {
        const int idx = it * 256 + tid;
        const int n = idx >> 3, k8 = (idx & 7) * 8;
        s8v o;
#pragma unroll
        for (int e = 0; e < 8; ++e) o[e] = (short)f2bf(t[k8 + e][n]);
        *(s8v*)&W2t[(size_t)(n0 + n) * 15360 + k0 + k8] = o;
      }
    }
    return;
  }

  const int lane = tid & 63, w = tid >> 6;
  const int l31 = lane & 31, hi = lane >> 5;
  const int h = bx >> 4;
  const int q0 = (bx & 15) * 128 + w * 32;
  const int q = q0 + l31;

  s8v qf[8];
  {
    const unsigned short* qb = qr + ((size_t)h * 2048 + q) * 128 + hi * 8;
#pragma unroll
    for (int ks = 0; ks < 8; ++ks) qf[ks] = *(const s8v*)(qb + ks * 16);
  }

  int koff[4], voff[4];
#pragma unroll
  for (int c = 0; c < 4; ++c) {
    const int ob = (w * 4 + c) * 1024 + lane * 16;
    const int row = ob >> 8;
    const int sl = (ob >> 4) & 15;
    const int ssl = sl ^ (row & 15);
    koff[c] = row * 128 + ssl * 8;
    const int dh = row * 2 + (ssl >> 3);
    voff[c] = dh * 2048 + (ssl & 7) * 8;
  }
  const unsigned short* krH = kr + (size_t)h * 2048 * 128;
  const unsigned short* vtH = vt + (size_t)h * 128 * 2048;

  f32x16 oacc[4];
#pragma unroll
  for (int rf = 0; rf < 4; ++rf)
#pragma unroll
    for (int e = 0; e < 16; ++e) oacc[rf][e] = 0.f;
  float m = -3e38f, l = 0.f;

#define ATT_STAGE(t)                                                        \
  do {                                                                      \
    char* kb_ = lds + ((t) & 1) * 32768;                                    \
    char* vb_ = kb_ + 16384;                                                \
    _Pragma("unroll") for (int c = 0; c < 4; ++c) {                         \
      gl_lds16(krH + (size_t)(t) * 8192 + koff[c], kb_ + (w * 4 + c) * 1024); \
      gl_lds16(vtH + (size_t)(t) * 64 + voff[c], vb_ + (w * 4 + c) * 1024);   \
    }                                                                       \
  } while (0)

  ATT_STAGE(0);
  __syncthreads();

  for (int t = 0; t < 32; ++t) {
    if (t + 1 < 32) ATT_STAGE(t + 1);
    char* kb = lds + (t & 1) * 32768;
    char* vb = kb + 16384;

    f32x16 st[2];
#pragma unroll
    for (int rf = 0; rf < 2; ++rf)
#pragma unroll
      for (int e = 0; e < 16; ++e) st[rf][e] = 0.f;
#pragma unroll
    for (int ks = 0; ks < 8; ++ks)
#pragma unroll
      for (int rf = 0; rf < 2; ++rf) {
        const int kvr = rf * 32 + l31;
        s8v kf = *(const s8v*)(kb + kvr * 256 + (((ks * 2 + hi) ^ (kvr & 15)) << 4));
        st[rf] = __builtin_amdgcn_mfma_f32_32x32x16_bf16(kf, qf[ks], st[rf], 0, 0, 0);
      }

    float pm = st[0][0];
#pragma unroll
    for (int rf = 0; rf < 2; ++rf)
#pragma unroll
      for (int e = 0; e < 16; ++e) pm = fmaxf(pm, st[rf][e]);
    pm = fmaxf(pm, __shfl_xor(pm, 32));
    if (__any(pm - m > 11.5f)) {   // defer-max (T13, log2 units)
      const float mn = fmaxf(m, pm);
      const float rs = exp2f(m - mn);
      l *= rs;
#pragma unroll
      for (int rf = 0; rf < 4; ++rf)
#pragma unroll
        for (int e = 0; e < 16; ++e) oacc[rf][e] *= rs;
      m = mn;
    }
    unsigned P2[16];
#pragma unroll
    for (int rb = 0; rb < 2; ++rb)
#pragma unroll
      for (int g = 0; g < 4; ++g) {
        const float e0 = exp2f(st[rb][4 * g + 0] - m);
        const float e1 = exp2f(st[rb][4 * g + 1] - m);
        const float e2 = exp2f(st[rb][4 * g + 2] - m);
        const float e3 = exp2f(st[rb][4 * g + 3] - m);
        l += (e0 + e1) + (e2 + e3);
        P2[rb * 8 + g * 2 + 0] = pk2bf(e0, e1);
        P2[rb * 8 + g * 2 + 1] = pk2bf(e2, e3);
      }

#pragma unroll
    for (int ks = 0; ks < 4; ++ks) {
      const int iA = ((2 * ks) >> 2) * 8 + ((2 * ks) & 3) * 2;
      const int iB = ((2 * ks + 1) >> 2) * 8 + ((2 * ks + 1) & 3) * 2;
      const unsigned s0 = hi ? P2[iA] : P2[iB];
      const unsigned s1 = hi ? P2[iA + 1] : P2[iB + 1];
      const unsigned r0 = (unsigned)__shfl_xor((int)s0, 32);
      const unsigned r1 = (unsigned)__shfl_xor((int)s1, 32);
      const unsigned o0 = hi ? P2[iB] : P2[iA];
      const unsigned o1 = hi ? P2[iB + 1] : P2[iA + 1];
      union { unsigned u[4]; s8v v; } pf;
      pf.u[0] = hi ? r0 : o0;
      pf.u[1] = hi ? r1 : o1;
      pf.u[2] = hi ? o0 : r0;
      pf.u[3] = hi ? o1 : r1;
#pragma unroll
      for (int rf = 0; rf < 4; ++rf) {
        const int dh = rf * 32 + l31, r = dh >> 1;
        const int sl = ((dh & 1) << 3) + ks * 2 + hi;
        s8v vf = *(const s8v*)(vb + r * 256 + ((sl ^ (r & 15)) << 4));
        oacc[rf] = __builtin_amdgcn_mfma_f32_32x32x16_bf16(vf, pf.v, oacc[rf], 0, 0, 0);
      }
    }
    __syncthreads();
  }

  const float lf = l + __shfl_xor(l, 32);
  const float inv = 1.f / lf;
  char* ep = lds + w * 8448;
#pragma unroll
  for (int rf = 0; rf < 4; ++rf)
#pragma unroll
    for (int g = 0; g < 4; ++g) {
      const unsigned u0 = pk2bf(oacc[rf][4 * g + 0] * inv, oacc[rf][4 * g + 1] * inv);
      const unsigned u1 = pk2bf(oacc[rf][4 * g + 2] * inv, oacc[rf][4 * g + 3] * inv);
      *(uint2*)(ep + l31 * 264 + rf * 64 + g * 16 + hi * 8) = make_uint2(u0, u1);
    }
  __syncthreads();
  const int c = lane & 15, l4b = lane >> 4;
#pragma unroll
  for (int pass = 0; pass < 8; ++pass) {
    const int qq = pass * 4 + l4b;
    const uint2 a2 = *(const uint2*)(ep + qq * 264 + c * 16);
    const uint2 b2 = *(const uint2*)(ep + qq * 264 + c * 16 + 8);
    *(uint4*)(A2 + (size_t)(q0 + qq) * 15360 + h * 128 + c * 8) =
        make_uint4(a2.x, a2.y, b2.x, b2.y);
  }
#undef ATT_STAGE
}

// ---------------- launch ----------------
extern "C" void kernel_launch(void* const* d_in, const int* in_sizes, int n_in,
                              void* d_out, int out_size, void* d_ws, size_t ws_size,
                              hipStream_t stream) {
  (void)in_sizes; (void)n_in; (void)out_size; (void)ws_size;
  const float* img    = (const float*)d_in[0];
  const float* vec    = (const float*)d_in[1];
  const float* pe     = (const float*)d_in[2];
  const float* mod_w  = (const float*)d_in[3];
  const float* mod_b  = (const float*)d_in[4];
  const float* lin1_w = (const float*)d_in[5];
  const float* lin1_b = (const float*)d_in[6];
  const float* lin2_w = (const float*)d_in[7];
  const float* lin2_b = (const float*)d_in[8];
  const float* q_s    = (const float*)d_in[9];
  const float* k_s    = (const float*)d_in[10];
  float* out = (float*)d_out;

  char* ws = (char*)d_ws;
  size_t off = 0;
  auto alloc = [&](size_t b) { size_t p = off; off += (b + 255) & ~(size_t)255; return p; };
  float* part          = (float*)(ws + alloc((size_t)8 * 9216 * 4));
  float* mod           = (float*)(ws + alloc((size_t)9216 * 4));
  unsigned short* x    = (unsigned short*)(ws + alloc((size_t)2048 * 3072 * 2));
  unsigned short* wT   = (unsigned short*)(ws + alloc((size_t)21504 * 3072 * 2));  // w1t then w2t
  unsigned short* proj = (unsigned short*)(ws + alloc((size_t)2048 * 21504 * 2));  // qkv uses 9216 stride
  unsigned short* qr   = (unsigned short*)(ws + alloc((size_t)24 * 2048 * 128 * 2));
  unsigned short* kr   = (unsigned short*)(ws + alloc((size_t)24 * 2048 * 128 * 2));
  unsigned short* vt   = (unsigned short*)(ws + alloc((size_t)24 * 128 * 2048 * 2));
  unsigned short* A2   = (unsigned short*)(ws + alloc((size_t)2048 * 15360 * 2));
  // gemm2 split-K(5) bf16 partials: 5 x 12,582,912 B = 62.9 MB, reuses the
  // dead proj+qr+kr+vt region.
  unsigned short* p2buf = (unsigned short*)proj;

  modvec_partial<<<dim3(36, 8), 256, 0, stream>>>(vec, mod_w, part);
  modvec_reduce<<<36, 256, 0, stream>>>(part, mod_b, mod);
  // merged: LN (2048 blocks) + lin1_w transpose (16128 blocks)
  ln_tr1_kernel<<<2048 + 16128, 256, 0, stream>>>(img, mod, x, lin1_w, wT);
  gemm256_kernel<0><<<672, 512, 0, stream>>>(x, wT, lin1_b, proj, A2, 3072, 21504, 48, 84);
  // merged: qk norm+rope (2048 blocks) + V transpose (384 blocks)
  qkv_prep_kernel<<<2048 + 384, 256, 0, stream>>>(proj, pe, q_s, k_s, qr, kr, vt);
  // merged: attn (384 blocks) + lin2_w transpose (5760 rider blocks x 2 tiles)
  attn_kernel<<<384 + 5760, 256, 0, stream>>>(qr, kr, vt, A2, lin2_w, wT);
  // gemm2: split-K=5 (best measured)
  gemm256_kernel<2><<<480, 512, 0, stream>>>(A2, wT, nullptr, p2buf, nullptr, 15360, 3072, 48, 12);
  reduce2_kernel<<<3072, 256, 0, stream>>>(p2buf, img, mod, lin2_b, out);
}